// Round 17
// baseline (278.660 us; speedup 1.0000x reference)
//
#include <hip/hip_runtime.h>
#include <hip/hip_fp16.h>
#include <hip/hip_cooperative_groups.h>

namespace cg = cooperative_groups;

#define NCOL 64
#define KDIM 128
#define NB 512          // coarse buckets (dst>>8, N<=131072)
#define CH 8192         // edges per chunk
#define GBLK_MAX 1024   // cooperative gather blocks upper bound
#define GMAX 13         // cached row-pairs per wave at 1024 blocks: ceil(100000/(2*1024*4))

typedef short bf16x8 __attribute__((ext_vector_type(8)));
typedef float f32x4 __attribute__((ext_vector_type(4)));
typedef float f32x2 __attribute__((ext_vector_type(2)));

__device__ __forceinline__ unsigned short f2bf(float f) {
    unsigned int u = __float_as_uint(f);
    return (unsigned short)((u + 0x7fffu + ((u >> 16) & 1u)) >> 16);
}
__device__ __forceinline__ float bflo(unsigned int u) { return __uint_as_float(u << 16); }
__device__ __forceinline__ float bfhi(unsigned int u) { return __uint_as_float(u & 0xffff0000u); }

// ---------------- K1: per-chunk 512-bin hist (dst only) -> gh[c][k]; bcnt fire-and-forget ----------------
__global__ __launch_bounds__(512) void hist_kernel(const int* __restrict__ dst,
                                                   int* __restrict__ bcnt,
                                                   int* __restrict__ gh, int E) {
    __shared__ int lh[NB];
    int tid = threadIdx.x;
    int c = blockIdx.x;
    if (tid < NB) lh[tid] = 0;
    __syncthreads();
    int c0 = c * CH;
    int cnt = min(CH, E - c0);
    for (int i = tid; i < cnt; i += 512)
        atomicAdd(&lh[dst[c0 + i] >> 8], 1);
    __syncthreads();
    if (tid < NB) {
        int v = lh[tid];
        gh[(size_t)c * NB + tid] = v;
        if (v) atomicAdd(&bcnt[tid], v);
    }
}

// ---------------- K2: per-bucket: bbase[k] from bcnt prefix, then scan chunks (in place) ----------------
__global__ __launch_bounds__(256) void chunk_scan(int* __restrict__ gh,
                                                  const int* __restrict__ bcnt,
                                                  int* __restrict__ bbase,
                                                  int* __restrict__ row_start,
                                                  int nchunks, int N, int E) {
    __shared__ int wsum[4];
    __shared__ int red[4];
    __shared__ int carry_s, tot_s;
    int k = blockIdx.x;
    int tid = threadIdx.x, lane = tid & 63, wv = tid >> 6;

    int v = 0;
    if (tid < k) v = bcnt[tid];
    if (tid + 256 < k) v += bcnt[tid + 256];
#pragma unroll
    for (int off = 1; off < 64; off <<= 1) v += __shfl_xor(v, off);
    if (lane == 0) red[wv] = v;
    __syncthreads();
    if (tid == 0) {
        int base = red[0] + red[1] + red[2] + red[3];
        carry_s = base;
        bbase[k] = base;
        if (k == 0) row_start[N] = E;
    }
    __syncthreads();

    for (int t0 = 0; t0 < nchunks; t0 += 256) {
        int c = t0 + tid;
        int x = (c < nchunks) ? gh[(size_t)c * NB + k] : 0;
        int inc = x;
#pragma unroll
        for (int off = 1; off < 64; off <<= 1) {
            int t = __shfl_up(inc, off); if (lane >= off) inc += t;
        }
        if (lane == 63) wsum[wv] = inc;
        __syncthreads();
        if (tid == 0) {
            int run = 0;
            for (int i = 0; i < 4; ++i) { int t = wsum[i]; wsum[i] = run; run += t; }
            tot_s = run;
        }
        __syncthreads();
        int excl = carry_s + wsum[wv] + inc - x;
        if (c < nchunks) gh[(size_t)c * NB + k] = excl;
        __syncthreads();
        if (tid == 0) carry_s += tot_s;
        __syncthreads();
    }
}

// ---------------- K3: scatter to pk via precomputed bases; outcnt hist here ----------------
__global__ __launch_bounds__(512) void scatter_pk(const int* __restrict__ src,
                                                  const int* __restrict__ dst,
                                                  const int* __restrict__ gh,
                                                  unsigned int* __restrict__ pk,
                                                  int* __restrict__ outcnt, int E) {
    __shared__ int lcur[NB];
    int tid = threadIdx.x;
    int c = blockIdx.x;
    if (tid < NB) lcur[tid] = gh[(size_t)c * NB + tid];
    __syncthreads();
    int c0 = c * CH;
    int cnt = min(CH, E - c0);
    for (int i = tid; i < cnt; i += 512) {
        int s = src[c0 + i], d = dst[c0 + i];
        atomicAdd(&outcnt[s], 1);
        int pos = atomicAdd(&lcur[d >> 8], 1);
        pk[pos] = ((unsigned)(d & 255) << 17) | (unsigned)s;
    }
}

// ---------------- K4: fine counting sort within bucket -> ssrc + row_start ----------------
__global__ __launch_bounds__(256) void fine_kernel(
    const unsigned int* __restrict__ pk, const int* __restrict__ bbase,
    int* __restrict__ row_start, int* __restrict__ ssrc, int E, int nbuck, int N) {
    __shared__ int hist[256];
    __shared__ int cur[256];
    __shared__ int wsum[4];
    int k = blockIdx.x;
    int tid = threadIdx.x, lane = tid & 63, wv = tid >> 6;
    int b0 = bbase[k];
    int b1 = (k + 1 < nbuck) ? bbase[k + 1] : E;

    hist[tid] = 0;
    __syncthreads();
    for (int i = b0 + tid; i < b1; i += 256)
        atomicAdd(&hist[pk[i] >> 17], 1);
    __syncthreads();

    int x = hist[tid], inc = x;
#pragma unroll
    for (int off = 1; off < 64; off <<= 1) {
        int t = __shfl_up(inc, off); if (lane >= off) inc += t;
    }
    if (lane == 63) wsum[wv] = inc;
    __syncthreads();
    if (tid == 0) { int run = 0; for (int i = 0; i < 4; ++i) { int t = wsum[i]; wsum[i] = run; run += t; } }
    __syncthreads();
    int excl = wsum[wv] + inc - x;

    int d = (k << 8) + tid;
    if (d < N) row_start[d] = b0 + excl;
    cur[tid] = b0 + excl;
    __syncthreads();

    for (int i = b0 + tid; i < b1; i += 256) {
        unsigned int p = pk[i];
        int pos = atomicAdd(&cur[p >> 17], 1);
        ssrc[pos] = (int)(p & 0x1FFFFu);
    }
}

// ---------------- K5: MFMA dual GEMM; h -> fp8 e4m3 col-strided; res -> bf16 packed pairs ----------------
__global__ __launch_bounds__(256) void matmul_mfma(
    const float* __restrict__ feat, const float* __restrict__ W,
    const float* __restrict__ RW, const float* __restrict__ res_b,
    const int* __restrict__ outcnt,
    unsigned int* __restrict__ hb8, unsigned int* __restrict__ r8, int N) {
    __shared__ bf16x8 Bf[2048];   // 32 KB
    int tid = threadIdx.x;
    for (int idx = tid; idx < 2048; idx += 256) {
        int mat = idx >> 10;
        int kc = (idx >> 8) & 3;
        int ct = (idx >> 6) & 3;
        int l = idx & 63;
        const float* Wp = mat ? RW : W;
        int kbase = kc * 32 + (l >> 4) * 8;
        int col = ct * 16 + (l & 15);
        bf16x8 t;
#pragma unroll
        for (int j = 0; j < 8; ++j)
            t[j] = (short)f2bf(Wp[(size_t)(kbase + j) * NCOL + col]);
        Bf[idx] = t;
    }
    __syncthreads();

    int lane = tid & 63;
    int wid = tid >> 6;
    int ntiles = (N + 15) >> 4;
    int tile = blockIdx.x * 4 + wid;
    if (tile >= ntiles) return;
    int c16 = lane & 15, kg = lane >> 4;

    float rbv[4];
#pragma unroll
    for (int ct = 0; ct < 4; ++ct) rbv[ct] = res_b[ct * 16 + c16];

    int tb = tile << 4;
    f32x4 acch[4], accr[4];
#pragma unroll
    for (int ct = 0; ct < 4; ++ct) {
        acch[ct] = (f32x4){0.f, 0.f, 0.f, 0.f};
        accr[ct] = (f32x4){0.f, 0.f, 0.f, 0.f};
    }

    int arow = tb + c16; if (arow >= N) arow = N - 1;
    const float* fp = feat + (size_t)arow * KDIM + kg * 8;
#pragma unroll
    for (int kc = 0; kc < 4; ++kc) {
        float4 a0 = *(const float4*)(fp + kc * 32);
        float4 a1 = *(const float4*)(fp + kc * 32 + 4);
        bf16x8 af;
        af[0] = (short)f2bf(a0.x); af[1] = (short)f2bf(a0.y);
        af[2] = (short)f2bf(a0.z); af[3] = (short)f2bf(a0.w);
        af[4] = (short)f2bf(a1.x); af[5] = (short)f2bf(a1.y);
        af[6] = (short)f2bf(a1.z); af[7] = (short)f2bf(a1.w);
#pragma unroll
        for (int ct = 0; ct < 4; ++ct) {
            acch[ct] = __builtin_amdgcn_mfma_f32_16x16x32_bf16(
                af, Bf[(kc * 4 + ct) * 64 + lane], acch[ct], 0, 0, 0);
            accr[ct] = __builtin_amdgcn_mfma_f32_16x16x32_bf16(
                af, Bf[1024 + (kc * 4 + ct) * 64 + lane], accr[ct], 0, 0, 0);
        }
    }

    float nrm[4];
#pragma unroll
    for (int r = 0; r < 4; ++r) {
        int rw = tb + kg * 4 + r; if (rw >= N) rw = N - 1;
        nrm[r] = rsqrtf(fmaxf((float)outcnt[rw], 1.0f));
    }
#pragma unroll
    for (int r = 0; r < 4; ++r) {
        int row = tb + kg * 4 + r;
        if (row < N) {
            unsigned int p = 0;
            p = (unsigned int)__builtin_amdgcn_cvt_pk_fp8_f32(
                    acch[0][r] * nrm[r], acch[1][r] * nrm[r], (int)p, false);
            p = (unsigned int)__builtin_amdgcn_cvt_pk_fp8_f32(
                    acch[2][r] * nrm[r], acch[3][r] * nrm[r], (int)p, true);
            hb8[(size_t)row * 16 + c16] = p;
            float q0 = fmaxf(accr[0][r] + rbv[0], 0.0f);
            float q1 = fmaxf(accr[1][r] + rbv[1], 0.0f);
            float q2 = fmaxf(accr[2][r] + rbv[2], 0.0f);
            float q3 = fmaxf(accr[3][r] + rbv[3], 0.0f);
            r8[(size_t)row * 32 + c16]      = ((unsigned)f2bf(q1) << 16) | f2bf(q0);
            r8[(size_t)row * 32 + 16 + c16] = ((unsigned)f2bf(q3) << 16) | f2bf(q2);
        }
    }
}

// ---------------- gather edge-step: 16 edges of one row ----------------
#define GATHER_ROW_STEP(eBase, eEnd, A0, A1, A2, A3)                                   \
    {                                                                                   \
        int e0 = (eBase) + e4, e1 = e0 + 4, e2 = e0 + 8, e3 = e0 + 12;                  \
        int i0 = (e0 < (eEnd)) ? ssrc[e0] : -1;                                         \
        int i1 = (e1 < (eEnd)) ? ssrc[e1] : -1;                                         \
        int i2 = (e2 < (eEnd)) ? ssrc[e2] : -1;                                         \
        int i3 = (e3 < (eEnd)) ? ssrc[e3] : -1;                                         \
        unsigned int v0 = (i0 >= 0) ? hb8[(size_t)i0 * 16 + dw] : 0u;                   \
        unsigned int v1 = (i1 >= 0) ? hb8[(size_t)i1 * 16 + dw] : 0u;                   \
        unsigned int v2 = (i2 >= 0) ? hb8[(size_t)i2 * 16 + dw] : 0u;                   \
        unsigned int v3 = (i3 >= 0) ? hb8[(size_t)i3 * 16 + dw] : 0u;                   \
        f32x2 l0 = __builtin_amdgcn_cvt_pk_f32_fp8((int)v0, false);                     \
        f32x2 h0 = __builtin_amdgcn_cvt_pk_f32_fp8((int)v0, true);                      \
        f32x2 l1 = __builtin_amdgcn_cvt_pk_f32_fp8((int)v1, false);                     \
        f32x2 h1 = __builtin_amdgcn_cvt_pk_f32_fp8((int)v1, true);                      \
        f32x2 l2 = __builtin_amdgcn_cvt_pk_f32_fp8((int)v2, false);                     \
        f32x2 h2 = __builtin_amdgcn_cvt_pk_f32_fp8((int)v2, true);                      \
        f32x2 l3 = __builtin_amdgcn_cvt_pk_f32_fp8((int)v3, false);                     \
        f32x2 h3 = __builtin_amdgcn_cvt_pk_f32_fp8((int)v3, true);                      \
        A0 += (l0[0] + l1[0]) + (l2[0] + l3[0]);                                        \
        A1 += (l0[1] + l1[1]) + (l2[1] + l3[1]);                                        \
        A2 += (h0[0] + h1[0]) + (h2[0] + h3[0]);                                        \
        A3 += (h0[1] + h1[1]) + (h2[1] + h3[1]);                                        \
    }

// computes one row-pair's raw (v0,v1) for this lane; returns dd (-1 if none)
__device__ __forceinline__ int gather_pair(
    const int* __restrict__ row_start, const int* __restrict__ ssrc,
    const unsigned int* __restrict__ hb8, const unsigned int* __restrict__ r8,
    float bcLo, float bcHi, int d0, int N,
    int e4, int dw, int rowSel, int ch, int colLo,
    float& v0o, float& v1o) {
    int d1 = d0 + 1;
    int a0 = row_start[d0], a1 = row_start[d0 + 1];
    int b0e = 0, b1e = 0;
    if (d1 < N) { b0e = a1; b1e = row_start[d1 + 1]; }

    float A0 = 0.f, A1 = 0.f, A2 = 0.f, A3 = 0.f;
    float B0 = 0.f, B1 = 0.f, B2 = 0.f, B3 = 0.f;
    int nit = max((a1 - a0 + 15) >> 4, (b1e - b0e + 15) >> 4);
    for (int it = 0; it < nit; ++it) {
        GATHER_ROW_STEP(a0 + it * 16, a1, A0, A1, A2, A3)
        GATHER_ROW_STEP(b0e + it * 16, b1e, B0, B1, B2, B3)
    }

#pragma unroll
    for (int off = 16; off <= 32; off <<= 1) {
        A0 += __shfl_xor(A0, off); A1 += __shfl_xor(A1, off);
        A2 += __shfl_xor(A2, off); A3 += __shfl_xor(A3, off);
        B0 += __shfl_xor(B0, off); B1 += __shfl_xor(B1, off);
        B2 += __shfl_xor(B2, off); B3 += __shfl_xor(B3, off);
    }

    int dd = d0 + rowSel;
    if (dd >= N) return -1;
    int deg = rowSel ? (b1e - b0e) : (a1 - a0);
    float nd = rsqrtf(fmaxf((float)deg, 1.0f));
    float vLo = rowSel ? (ch ? B2 : B0) : (ch ? A2 : A0);
    float vHi = rowSel ? (ch ? B3 : B1) : (ch ? A3 : A1);
    unsigned int rr = r8[(size_t)dd * 32 + ch * 16 + dw];
    v0o = fmaxf(vLo * nd + bcLo, 0.f) + bflo(rr);
    v1o = fmaxf(vHi * nd + bcHi, 0.f) + bfhi(rr);
    return dd;
}

// ---------------- K6 (fallback a): plain gather -> y raw + BN stats ----------------
__global__ __launch_bounds__(256) void gather_kernel(
    const int* __restrict__ row_start, const int* __restrict__ ssrc,
    const unsigned int* __restrict__ hb8, const unsigned int* __restrict__ r8,
    const float* __restrict__ b,
    float* __restrict__ y, float* __restrict__ stats, int N) {
    int tid = threadIdx.x, lane = tid & 63, wid = tid >> 6;
    int e4 = lane >> 4, dw = lane & 15;
    int rowSel = e4 >> 1, ch = e4 & 1;
    int colLo = (ch << 5) + dw;
    int wave = blockIdx.x * 4 + wid;
    int nwaves = gridDim.x * 4;

    float bcLo = b[colLo], bcHi = b[colLo + 16];
    float bnLo = 0.f, bnHi = 0.f, bnsqLo = 0.f, bnsqHi = 0.f;

    for (int d0 = wave * 2; d0 < N; d0 += 2 * nwaves) {
        float v0, v1;
        int dd = gather_pair(row_start, ssrc, hb8, r8, bcLo, bcHi,
                             d0, N, e4, dw, rowSel, ch, colLo, v0, v1);
        if (dd >= 0) {
            float* yp = &y[(size_t)dd * NCOL + colLo];
            yp[0] = v0;
            yp[16] = v1;
            bnLo += v0; bnsqLo += v0 * v0;
            bnHi += v1; bnsqHi += v1 * v1;
        }
    }

    bnLo += __shfl_xor(bnLo, 32); bnsqLo += __shfl_xor(bnsqLo, 32);
    bnHi += __shfl_xor(bnHi, 32); bnsqHi += __shfl_xor(bnsqHi, 32);

    __shared__ float bnred[4][128];
    if (lane < 32) {
        bnred[wid][colLo] = bnLo;
        bnred[wid][colLo + 16] = bnHi;
        bnred[wid][64 + colLo] = bnsqLo;
        bnred[wid][64 + colLo + 16] = bnsqHi;
    }
    __syncthreads();
    if (tid < 128) {
        float v = bnred[0][tid] + bnred[1][tid] + bnred[2][tid] + bnred[3][tid];
        unsafeAtomicAdd(&stats[tid], v);
    }
}

// ---------------- K7 (fallback b): BN apply ----------------
__global__ __launch_bounds__(256) void apply_kernel(float* __restrict__ y,
                                                    const float* __restrict__ stats,
                                                    const float* __restrict__ gamma,
                                                    const float* __restrict__ beta,
                                                    float invN, int total4) {
    __shared__ float sc[64], sh[64];
    int tid = threadIdx.x;
    if (tid < 64) {
        float mean = stats[tid] * invN;
        float var = stats[64 + tid] * invN - mean * mean;
        float s = gamma[tid] * rsqrtf(var + 1e-5f);
        sc[tid] = s;
        sh[tid] = beta[tid] - mean * s;
    }
    __syncthreads();
    int i = blockIdx.x * blockDim.x + tid;
    int stride = gridDim.x * blockDim.x;
    float4* y4 = (float4*)y;
    for (; i < total4; i += stride) {
        float4 v = y4[i];
        int cbase = (i & 15) << 2;
        float4 s = *(const float4*)&sc[cbase];
        float4 t = *(const float4*)&sh[cbase];
        v.x = v.x * s.x + t.x;
        v.y = v.y * s.y + t.y;
        v.z = v.z * s.z + t.z;
        v.w = v.w * s.w + t.w;
        y4[i] = v;
    }
}

// ---------------- K6' : cooperative fused gather + BN stats + grid sync + BN apply ----------------
// Works for ANY grid size: first GMAX row-pairs per wave cached in registers,
// the rest go through the raw-write + re-read tail path.
__global__ __launch_bounds__(256, 4) void gather_fused(
    const int* __restrict__ row_start, const int* __restrict__ ssrc,
    const unsigned int* __restrict__ hb8, const unsigned int* __restrict__ r8,
    const float* __restrict__ b, const float* __restrict__ gamma,
    const float* __restrict__ beta,
    float* __restrict__ y, float* __restrict__ stats, int N, float invN) {
    int tid = threadIdx.x, lane = tid & 63, wid = tid >> 6;
    int e4 = lane >> 4, dw = lane & 15;
    int rowSel = e4 >> 1, ch = e4 & 1;
    int colLo = (ch << 5) + dw;
    int wave = blockIdx.x * 4 + wid;
    int nwaves = gridDim.x * 4;
    int stride = 2 * nwaves;

    float bcLo = b[colLo], bcHi = b[colLo + 16];
    float bnLo = 0.f, bnHi = 0.f, bnsqLo = 0.f, bnsqHi = 0.f;
    float sv0[GMAX], sv1[GMAX];
#pragma unroll
    for (int k = 0; k < GMAX; ++k) { sv0[k] = 0.f; sv1[k] = 0.f; }

    // --- pre-phase: cached rows ---
#pragma unroll
    for (int k = 0; k < GMAX; ++k) {
        int d0 = wave * 2 + k * stride;
        if (d0 < N) {
            float v0, v1;
            int dd = gather_pair(row_start, ssrc, hb8, r8, bcLo, bcHi,
                                 d0, N, e4, dw, rowSel, ch, colLo, v0, v1);
            if (dd >= 0) {
                sv0[k] = v0; sv1[k] = v1;
                bnLo += v0; bnsqLo += v0 * v0;
                bnHi += v1; bnsqHi += v1 * v1;
            }
        }
    }
    // --- tail rows: raw write, re-read in post-phase ---
    for (int d0 = wave * 2 + GMAX * stride; d0 < N; d0 += stride) {
        float v0, v1;
        int dd = gather_pair(row_start, ssrc, hb8, r8, bcLo, bcHi,
                             d0, N, e4, dw, rowSel, ch, colLo, v0, v1);
        if (dd >= 0) {
            float* yp = &y[(size_t)dd * NCOL + colLo];
            yp[0] = v0; yp[16] = v1;
            bnLo += v0; bnsqLo += v0 * v0;
            bnHi += v1; bnsqHi += v1 * v1;
        }
    }

    bnLo += __shfl_xor(bnLo, 32); bnsqLo += __shfl_xor(bnsqLo, 32);
    bnHi += __shfl_xor(bnHi, 32); bnsqHi += __shfl_xor(bnsqHi, 32);

    __shared__ float bnred[4][128];
    if (lane < 32) {
        bnred[wid][colLo] = bnLo;
        bnred[wid][colLo + 16] = bnHi;
        bnred[wid][64 + colLo] = bnsqLo;
        bnred[wid][64 + colLo + 16] = bnsqHi;
    }
    __syncthreads();
    if (tid < 128) {
        float v = bnred[0][tid] + bnred[1][tid] + bnred[2][tid] + bnred[3][tid];
        unsafeAtomicAdd(&stats[tid], v);
    }

    cg::this_grid().sync();

    __shared__ float sc[64], sh[64];
    if (tid < 64) {
        float mean = stats[tid] * invN;
        float var = stats[64 + tid] * invN - mean * mean;
        float s = gamma[tid] * rsqrtf(var + 1e-5f);
        sc[tid] = s;
        sh[tid] = beta[tid] - mean * s;
    }
    __syncthreads();
    float scLo = sc[colLo], shLo = sh[colLo];
    float scHi = sc[colLo + 16], shHi = sh[colLo + 16];

#pragma unroll
    for (int k = 0; k < GMAX; ++k) {
        int d0 = wave * 2 + k * stride;
        int dd = d0 + rowSel;
        if (d0 < N && dd < N) {
            float* yp = &y[(size_t)dd * NCOL + colLo];
            yp[0]  = sv0[k] * scLo + shLo;
            yp[16] = sv1[k] * scHi + shHi;
        }
    }
    for (int d0 = wave * 2 + GMAX * stride; d0 < N; d0 += stride) {
        int dd = d0 + rowSel;
        if (dd < N) {
            float* yp = &y[(size_t)dd * NCOL + colLo];
            yp[0]  = yp[0] * scLo + shLo;
            yp[16] = yp[16] * scHi + shHi;
        }
    }
}

extern "C" void kernel_launch(void* const* d_in, const int* in_sizes, int n_in,
                              void* d_out, int out_size, void* d_ws, size_t ws_size,
                              hipStream_t stream) {
    const float* feat  = (const float*)d_in[0];
    const int*   src   = (const int*)d_in[1];
    const int*   dst   = (const int*)d_in[2];
    const float* W     = (const float*)d_in[3];
    const float* b     = (const float*)d_in[4];
    const float* RW    = (const float*)d_in[5];
    const float* rb    = (const float*)d_in[6];
    const float* gamma = (const float*)d_in[7];
    const float* beta  = (const float*)d_in[8];

    int N = in_sizes[0] / KDIM;
    int E = in_sizes[1];
    float* out = (float*)d_out;
    int nbuck = (N + 255) >> 8;           // 391 for N=100000
    int nchunks = (E + CH - 1) / CH;      // 196 for E=1.6M

    // workspace layout
    char* wsb = (char*)d_ws;
    unsigned int* hb8 = (unsigned int*)wsb;                wsb += (size_t)N * 16 * 4;
    unsigned int* r8  = (unsigned int*)wsb;                wsb += (size_t)N * 32 * 4;
    unsigned int* pk  = (unsigned int*)wsb;                wsb += (size_t)E * 4;
    int*   ssrc     = (int*)wsb;                           wsb += (size_t)E * 4;
    int*   row_start= (int*)wsb;                           wsb += (size_t)(N + 1) * 4;
    int*   outcnt   = (int*)wsb;                           wsb += (size_t)N * 4;
    float* stats    = (float*)wsb;                         wsb += 256 * 4;
    int*   bcnt     = (int*)wsb;                           wsb += NB * 4;
    int*   bbase    = (int*)wsb;                           wsb += NB * 4;
    int*   gh       = (int*)wsb;                           // nchunks*NB ints

    // zero outcnt | stats | bcnt (contiguous)
    hipMemsetAsync(outcnt, 0, ((size_t)N + 256 + NB) * 4, stream);

    hist_kernel<<<nchunks, 512, 0, stream>>>(dst, bcnt, gh, E);
    chunk_scan<<<NB, 256, 0, stream>>>(gh, bcnt, bbase, row_start, nchunks, N, E);
    scatter_pk<<<nchunks, 512, 0, stream>>>(src, dst, gh, pk, outcnt, E);
    matmul_mfma<<<(((N + 15) >> 4) + 3) / 4, 256, 0, stream>>>(feat, W, RW, rb, outcnt, hb8, r8, N);
    fine_kernel<<<nbuck, 256, 0, stream>>>(pk, bbase, row_start, ssrc, E, nbuck, N);

    float invN = 1.0f / (float)N;

    // query cooperative co-residency; adapt grid, fall back on any failure
    int blocksPerCU = 0;
    hipError_t qerr = hipOccupancyMaxActiveBlocksPerMultiprocessor(
        &blocksPerCU, (const void*)gather_fused, 256, 0);
    int coopGrid = 0;
    if (qerr == hipSuccess && blocksPerCU > 0)
        coopGrid = min(GBLK_MAX, blocksPerCU * 256);

    bool fused_ok = false;
    if (coopGrid >= 256) {
        void* args[] = {(void*)&row_start, (void*)&ssrc, (void*)&hb8, (void*)&r8,
                        (void*)&b, (void*)&gamma, (void*)&beta,
                        (void*)&out, (void*)&stats, (void*)&N, (void*)&invN};
        hipError_t cerr = hipLaunchCooperativeKernel((void*)gather_fused,
                                                     dim3(coopGrid), dim3(256),
                                                     args, 0, stream);
        fused_ok = (cerr == hipSuccess);
    }
    if (!fused_ok) {
        gather_kernel<<<2048, 256, 0, stream>>>(row_start, ssrc, hb8, r8, b, out, stats, N);
        apply_kernel<<<2048, 256, 0, stream>>>(out, stats, gamma, beta, invN, (N * NCOL) / 4);
    }
}

// Round 18
// 228.358 us; speedup vs baseline: 1.2203x; 1.2203x over previous
//
#include <hip/hip_runtime.h>
#include <hip/hip_fp16.h>

#define NCOL 64
#define KDIM 128
#define NB 512          // coarse buckets (dst>>8, N<=131072)
#define CH 8192         // edges per chunk

typedef short bf16x8 __attribute__((ext_vector_type(8)));
typedef float f32x4 __attribute__((ext_vector_type(4)));
typedef float f32x2 __attribute__((ext_vector_type(2)));

__device__ __forceinline__ unsigned short f2bf(float f) {
    unsigned int u = __float_as_uint(f);
    return (unsigned short)((u + 0x7fffu + ((u >> 16) & 1u)) >> 16);
}
__device__ __forceinline__ float bflo(unsigned int u) { return __uint_as_float(u << 16); }
__device__ __forceinline__ float bfhi(unsigned int u) { return __uint_as_float(u & 0xffff0000u); }

// ---------------- K1: per-chunk 512-bin hist (dst only) -> gh[c][k]; bcnt fire-and-forget ----------------
__global__ __launch_bounds__(512) void hist_kernel(const int* __restrict__ dst,
                                                   int* __restrict__ bcnt,
                                                   int* __restrict__ gh, int E) {
    __shared__ int lh[NB];
    int tid = threadIdx.x;
    int c = blockIdx.x;
    if (tid < NB) lh[tid] = 0;
    __syncthreads();
    int c0 = c * CH;
    int cnt = min(CH, E - c0);
    for (int i = tid; i < cnt; i += 512)
        atomicAdd(&lh[dst[c0 + i] >> 8], 1);
    __syncthreads();
    if (tid < NB) {
        int v = lh[tid];
        gh[(size_t)c * NB + tid] = v;
        if (v) atomicAdd(&bcnt[tid], v);
    }
}

// ---------------- K2: per-bucket: bbase[k] from bcnt prefix, then scan chunks (in place) ----------------
__global__ __launch_bounds__(256) void chunk_scan(int* __restrict__ gh,
                                                  const int* __restrict__ bcnt,
                                                  int* __restrict__ bbase,
                                                  int* __restrict__ row_start,
                                                  int nchunks, int N, int E) {
    __shared__ int wsum[4];
    __shared__ int red[4];
    __shared__ int carry_s, tot_s;
    int k = blockIdx.x;
    int tid = threadIdx.x, lane = tid & 63, wv = tid >> 6;

    int v = 0;
    if (tid < k) v = bcnt[tid];
    if (tid + 256 < k) v += bcnt[tid + 256];
#pragma unroll
    for (int off = 1; off < 64; off <<= 1) v += __shfl_xor(v, off);
    if (lane == 0) red[wv] = v;
    __syncthreads();
    if (tid == 0) {
        int base = red[0] + red[1] + red[2] + red[3];
        carry_s = base;
        bbase[k] = base;
        if (k == 0) row_start[N] = E;
    }
    __syncthreads();

    for (int t0 = 0; t0 < nchunks; t0 += 256) {
        int c = t0 + tid;
        int x = (c < nchunks) ? gh[(size_t)c * NB + k] : 0;
        int inc = x;
#pragma unroll
        for (int off = 1; off < 64; off <<= 1) {
            int t = __shfl_up(inc, off); if (lane >= off) inc += t;
        }
        if (lane == 63) wsum[wv] = inc;
        __syncthreads();
        if (tid == 0) {
            int run = 0;
            for (int i = 0; i < 4; ++i) { int t = wsum[i]; wsum[i] = run; run += t; }
            tot_s = run;
        }
        __syncthreads();
        int excl = carry_s + wsum[wv] + inc - x;
        if (c < nchunks) gh[(size_t)c * NB + k] = excl;
        __syncthreads();
        if (tid == 0) carry_s += tot_s;
        __syncthreads();
    }
}

// ---------------- K3: scatter to pk via precomputed bases; outcnt hist here (src already read) ----------------
__global__ __launch_bounds__(512) void scatter_pk(const int* __restrict__ src,
                                                  const int* __restrict__ dst,
                                                  const int* __restrict__ gh,
                                                  unsigned int* __restrict__ pk,
                                                  int* __restrict__ outcnt, int E) {
    __shared__ int lcur[NB];
    int tid = threadIdx.x;
    int c = blockIdx.x;
    if (tid < NB) lcur[tid] = gh[(size_t)c * NB + tid];
    __syncthreads();
    int c0 = c * CH;
    int cnt = min(CH, E - c0);
    for (int i = tid; i < cnt; i += 512) {
        int s = src[c0 + i], d = dst[c0 + i];
        atomicAdd(&outcnt[s], 1);
        int pos = atomicAdd(&lcur[d >> 8], 1);
        pk[pos] = ((unsigned)(d & 255) << 17) | (unsigned)s;
    }
}

// ---------------- K4: fine counting sort within bucket -> ssrc + row_start ----------------
__global__ __launch_bounds__(256) void fine_kernel(
    const unsigned int* __restrict__ pk, const int* __restrict__ bbase,
    int* __restrict__ row_start, int* __restrict__ ssrc, int E, int nbuck, int N) {
    __shared__ int hist[256];
    __shared__ int cur[256];
    __shared__ int wsum[4];
    int k = blockIdx.x;
    int tid = threadIdx.x, lane = tid & 63, wv = tid >> 6;
    int b0 = bbase[k];
    int b1 = (k + 1 < nbuck) ? bbase[k + 1] : E;

    hist[tid] = 0;
    __syncthreads();
    for (int i = b0 + tid; i < b1; i += 256)
        atomicAdd(&hist[pk[i] >> 17], 1);
    __syncthreads();

    int x = hist[tid], inc = x;
#pragma unroll
    for (int off = 1; off < 64; off <<= 1) {
        int t = __shfl_up(inc, off); if (lane >= off) inc += t;
    }
    if (lane == 63) wsum[wv] = inc;
    __syncthreads();
    if (tid == 0) { int run = 0; for (int i = 0; i < 4; ++i) { int t = wsum[i]; wsum[i] = run; run += t; } }
    __syncthreads();
    int excl = wsum[wv] + inc - x;

    int d = (k << 8) + tid;
    if (d < N) row_start[d] = b0 + excl;
    cur[tid] = b0 + excl;
    __syncthreads();

    for (int i = b0 + tid; i < b1; i += 256) {
        unsigned int p = pk[i];
        int pos = atomicAdd(&cur[p >> 17], 1);
        ssrc[pos] = (int)(p & 0x1FFFFu);
    }
}

// ---------------- K5: MFMA dual GEMM; h -> fp8 e4m3 col-strided; res -> bf16 packed pairs ----------------
// r8[row*32 + c16]      packs (col c16,    col 16+c16)
// r8[row*32 + 16 + c16] packs (col 32+c16, col 48+c16)
__global__ __launch_bounds__(256) void matmul_mfma(
    const float* __restrict__ feat, const float* __restrict__ W,
    const float* __restrict__ RW, const float* __restrict__ res_b,
    const int* __restrict__ outcnt,
    unsigned int* __restrict__ hb8, unsigned int* __restrict__ r8, int N) {
    __shared__ bf16x8 Bf[2048];   // 32 KB
    int tid = threadIdx.x;
    for (int idx = tid; idx < 2048; idx += 256) {
        int mat = idx >> 10;
        int kc = (idx >> 8) & 3;
        int ct = (idx >> 6) & 3;
        int l = idx & 63;
        const float* Wp = mat ? RW : W;
        int kbase = kc * 32 + (l >> 4) * 8;
        int col = ct * 16 + (l & 15);
        bf16x8 t;
#pragma unroll
        for (int j = 0; j < 8; ++j)
            t[j] = (short)f2bf(Wp[(size_t)(kbase + j) * NCOL + col]);
        Bf[idx] = t;
    }
    __syncthreads();

    int lane = tid & 63;
    int wid = tid >> 6;
    int ntiles = (N + 15) >> 4;
    int tile = blockIdx.x * 4 + wid;
    if (tile >= ntiles) return;
    int c16 = lane & 15, kg = lane >> 4;

    float rbv[4];
#pragma unroll
    for (int ct = 0; ct < 4; ++ct) rbv[ct] = res_b[ct * 16 + c16];

    int tb = tile << 4;
    f32x4 acch[4], accr[4];
#pragma unroll
    for (int ct = 0; ct < 4; ++ct) {
        acch[ct] = (f32x4){0.f, 0.f, 0.f, 0.f};
        accr[ct] = (f32x4){0.f, 0.f, 0.f, 0.f};
    }

    int arow = tb + c16; if (arow >= N) arow = N - 1;
    const float* fp = feat + (size_t)arow * KDIM + kg * 8;
#pragma unroll
    for (int kc = 0; kc < 4; ++kc) {
        float4 a0 = *(const float4*)(fp + kc * 32);
        float4 a1 = *(const float4*)(fp + kc * 32 + 4);
        bf16x8 af;
        af[0] = (short)f2bf(a0.x); af[1] = (short)f2bf(a0.y);
        af[2] = (short)f2bf(a0.z); af[3] = (short)f2bf(a0.w);
        af[4] = (short)f2bf(a1.x); af[5] = (short)f2bf(a1.y);
        af[6] = (short)f2bf(a1.z); af[7] = (short)f2bf(a1.w);
#pragma unroll
        for (int ct = 0; ct < 4; ++ct) {
            acch[ct] = __builtin_amdgcn_mfma_f32_16x16x32_bf16(
                af, Bf[(kc * 4 + ct) * 64 + lane], acch[ct], 0, 0, 0);
            accr[ct] = __builtin_amdgcn_mfma_f32_16x16x32_bf16(
                af, Bf[1024 + (kc * 4 + ct) * 64 + lane], accr[ct], 0, 0, 0);
        }
    }

    float nrm[4];
#pragma unroll
    for (int r = 0; r < 4; ++r) {
        int rw = tb + kg * 4 + r; if (rw >= N) rw = N - 1;
        nrm[r] = rsqrtf(fmaxf((float)outcnt[rw], 1.0f));
    }
#pragma unroll
    for (int r = 0; r < 4; ++r) {
        int row = tb + kg * 4 + r;
        if (row < N) {
            unsigned int p = 0;
            p = (unsigned int)__builtin_amdgcn_cvt_pk_fp8_f32(
                    acch[0][r] * nrm[r], acch[1][r] * nrm[r], (int)p, false);
            p = (unsigned int)__builtin_amdgcn_cvt_pk_fp8_f32(
                    acch[2][r] * nrm[r], acch[3][r] * nrm[r], (int)p, true);
            hb8[(size_t)row * 16 + c16] = p;
            float q0 = fmaxf(accr[0][r] + rbv[0], 0.0f);
            float q1 = fmaxf(accr[1][r] + rbv[1], 0.0f);
            float q2 = fmaxf(accr[2][r] + rbv[2], 0.0f);
            float q3 = fmaxf(accr[3][r] + rbv[3], 0.0f);
            r8[(size_t)row * 32 + c16]      = ((unsigned)f2bf(q1) << 16) | f2bf(q0);
            r8[(size_t)row * 32 + 16 + c16] = ((unsigned)f2bf(q3) << 16) | f2bf(q2);
        }
    }
}

// ---------------- gather edge-step: 16 edges of one row ----------------
#define GATHER_ROW_STEP(eBase, eEnd, A0, A1, A2, A3)                                   \
    {                                                                                   \
        int e0 = (eBase) + e4, e1 = e0 + 4, e2 = e0 + 8, e3 = e0 + 12;                  \
        int i0 = (e0 < (eEnd)) ? ssrc[e0] : -1;                                         \
        int i1 = (e1 < (eEnd)) ? ssrc[e1] : -1;                                         \
        int i2 = (e2 < (eEnd)) ? ssrc[e2] : -1;                                         \
        int i3 = (e3 < (eEnd)) ? ssrc[e3] : -1;                                         \
        unsigned int v0 = (i0 >= 0) ? hb8[(size_t)i0 * 16 + dw] : 0u;                   \
        unsigned int v1 = (i1 >= 0) ? hb8[(size_t)i1 * 16 + dw] : 0u;                   \
        unsigned int v2 = (i2 >= 0) ? hb8[(size_t)i2 * 16 + dw] : 0u;                   \
        unsigned int v3 = (i3 >= 0) ? hb8[(size_t)i3 * 16 + dw] : 0u;                   \
        f32x2 l0 = __builtin_amdgcn_cvt_pk_f32_fp8((int)v0, false);                     \
        f32x2 h0 = __builtin_amdgcn_cvt_pk_f32_fp8((int)v0, true);                      \
        f32x2 l1 = __builtin_amdgcn_cvt_pk_f32_fp8((int)v1, false);                     \
        f32x2 h1 = __builtin_amdgcn_cvt_pk_f32_fp8((int)v1, true);                      \
        f32x2 l2 = __builtin_amdgcn_cvt_pk_f32_fp8((int)v2, false);                     \
        f32x2 h2 = __builtin_amdgcn_cvt_pk_f32_fp8((int)v2, true);                      \
        f32x2 l3 = __builtin_amdgcn_cvt_pk_f32_fp8((int)v3, false);                     \
        f32x2 h3 = __builtin_amdgcn_cvt_pk_f32_fp8((int)v3, true);                      \
        A0 += (l0[0] + l1[0]) + (l2[0] + l3[0]);                                        \
        A1 += (l0[1] + l1[1]) + (l2[1] + l3[1]);                                        \
        A2 += (h0[0] + h1[0]) + (h2[0] + h3[0]);                                        \
        A3 += (h0[1] + h1[1]) + (h2[1] + h3[1]);                                        \
    }

// ---------------- K6: single-pass gather, bf16 res read, f32 y write ----------------
__global__ __launch_bounds__(256) void gather_kernel(
    const int* __restrict__ row_start, const int* __restrict__ ssrc,
    const unsigned int* __restrict__ hb8, const unsigned int* __restrict__ r8,
    const float* __restrict__ b,
    float* __restrict__ y, float* __restrict__ stats, int N) {
    int tid = threadIdx.x, lane = tid & 63, wid = tid >> 6;
    int e4 = lane >> 4, dw = lane & 15;
    int rowSel = e4 >> 1, ch = e4 & 1;
    int colLo = (ch << 5) + dw;            // {dw, 32+dw}
    int wave = blockIdx.x * 4 + wid;
    int nwaves = gridDim.x * 4;

    float bcLo = b[colLo], bcHi = b[colLo + 16];
    float bnLo = 0.f, bnHi = 0.f, bnsqLo = 0.f, bnsqHi = 0.f;

    for (int d0 = wave * 2; d0 < N; d0 += 2 * nwaves) {
        int d1 = d0 + 1;
        int a0 = row_start[d0], a1 = row_start[d0 + 1];
        int b0e = 0, b1e = 0;
        if (d1 < N) { b0e = a1; b1e = row_start[d1 + 1]; }

        float A0 = 0.f, A1 = 0.f, A2 = 0.f, A3 = 0.f;
        float B0 = 0.f, B1 = 0.f, B2 = 0.f, B3 = 0.f;
        int nit = max((a1 - a0 + 15) >> 4, (b1e - b0e + 15) >> 4);
        for (int it = 0; it < nit; ++it) {
            GATHER_ROW_STEP(a0 + it * 16, a1, A0, A1, A2, A3)
            GATHER_ROW_STEP(b0e + it * 16, b1e, B0, B1, B2, B3)
        }

#pragma unroll
        for (int off = 16; off <= 32; off <<= 1) {
            A0 += __shfl_xor(A0, off); A1 += __shfl_xor(A1, off);
            A2 += __shfl_xor(A2, off); A3 += __shfl_xor(A3, off);
            B0 += __shfl_xor(B0, off); B1 += __shfl_xor(B1, off);
            B2 += __shfl_xor(B2, off); B3 += __shfl_xor(B3, off);
        }

        int dd = d0 + rowSel;
        if (dd < N) {
            int deg = rowSel ? (b1e - b0e) : (a1 - a0);
            float nd = rsqrtf(fmaxf((float)deg, 1.0f));
            float vLo = rowSel ? (ch ? B2 : B0) : (ch ? A2 : A0);
            float vHi = rowSel ? (ch ? B3 : B1) : (ch ? A3 : A1);
            unsigned int rr = r8[(size_t)dd * 32 + ch * 16 + dw];
            float v0 = fmaxf(vLo * nd + bcLo, 0.f) + bflo(rr);
            float v1 = fmaxf(vHi * nd + bcHi, 0.f) + bfhi(rr);
            float* yp = &y[(size_t)dd * NCOL + colLo];
            yp[0] = v0;
            yp[16] = v1;
            bnLo += v0; bnsqLo += v0 * v0;
            bnHi += v1; bnsqHi += v1 * v1;
        }
    }

    bnLo += __shfl_xor(bnLo, 32); bnsqLo += __shfl_xor(bnsqLo, 32);
    bnHi += __shfl_xor(bnHi, 32); bnsqHi += __shfl_xor(bnsqHi, 32);

    __shared__ float bnred[4][128];
    if (lane < 32) {
        bnred[wid][colLo] = bnLo;
        bnred[wid][colLo + 16] = bnHi;
        bnred[wid][64 + colLo] = bnsqLo;
        bnred[wid][64 + colLo + 16] = bnsqHi;
    }
    __syncthreads();
    if (tid < 128) {
        float v = bnred[0][tid] + bnred[1][tid] + bnred[2][tid] + bnred[3][tid];
        unsafeAtomicAdd(&stats[tid], v);
    }
}

// ---------------- K7: BN apply (params computed in-block, in place, float4) ----------------
__global__ __launch_bounds__(256) void apply_kernel(float* __restrict__ y,
                                                    const float* __restrict__ stats,
                                                    const float* __restrict__ gamma,
                                                    const float* __restrict__ beta,
                                                    float invN, int total4) {
    __shared__ float sc[64], sh[64];
    int tid = threadIdx.x;
    if (tid < 64) {
        float mean = stats[tid] * invN;
        float var = stats[64 + tid] * invN - mean * mean;
        float s = gamma[tid] * rsqrtf(var + 1e-5f);
        sc[tid] = s;
        sh[tid] = beta[tid] - mean * s;
    }
    __syncthreads();
    int i = blockIdx.x * blockDim.x + tid;
    int stride = gridDim.x * blockDim.x;
    float4* y4 = (float4*)y;
    for (; i < total4; i += stride) {
        float4 v = y4[i];
        int cbase = (i & 15) << 2;
        float4 s = *(const float4*)&sc[cbase];
        float4 t = *(const float4*)&sh[cbase];
        v.x = v.x * s.x + t.x;
        v.y = v.y * s.y + t.y;
        v.z = v.z * s.z + t.z;
        v.w = v.w * s.w + t.w;
        y4[i] = v;
    }
}

extern "C" void kernel_launch(void* const* d_in, const int* in_sizes, int n_in,
                              void* d_out, int out_size, void* d_ws, size_t ws_size,
                              hipStream_t stream) {
    const float* feat  = (const float*)d_in[0];
    const int*   src   = (const int*)d_in[1];
    const int*   dst   = (const int*)d_in[2];
    const float* W     = (const float*)d_in[3];
    const float* b     = (const float*)d_in[4];
    const float* RW    = (const float*)d_in[5];
    const float* rb    = (const float*)d_in[6];
    const float* gamma = (const float*)d_in[7];
    const float* beta  = (const float*)d_in[8];

    int N = in_sizes[0] / KDIM;
    int E = in_sizes[1];
    float* out = (float*)d_out;
    int nbuck = (N + 255) >> 8;           // 391 for N=100000
    int nchunks = (E + CH - 1) / CH;      // 196 for E=1.6M

    // workspace layout
    char* wsb = (char*)d_ws;
    unsigned int* hb8 = (unsigned int*)wsb;                wsb += (size_t)N * 16 * 4;
    unsigned int* r8  = (unsigned int*)wsb;                wsb += (size_t)N * 32 * 4;
    unsigned int* pk  = (unsigned int*)wsb;                wsb += (size_t)E * 4;
    int*   ssrc     = (int*)wsb;                           wsb += (size_t)E * 4;
    int*   row_start= (int*)wsb;                           wsb += (size_t)(N + 1) * 4;
    int*   outcnt   = (int*)wsb;                           wsb += (size_t)N * 4;
    float* stats    = (float*)wsb;                         wsb += 256 * 4;
    int*   bcnt     = (int*)wsb;                           wsb += NB * 4;
    int*   bbase    = (int*)wsb;                           wsb += NB * 4;
    int*   gh       = (int*)wsb;                           // nchunks*NB ints

    // zero outcnt | stats | bcnt (contiguous)
    hipMemsetAsync(outcnt, 0, ((size_t)N + 256 + NB) * 4, stream);

    hist_kernel<<<nchunks, 512, 0, stream>>>(dst, bcnt, gh, E);
    chunk_scan<<<NB, 256, 0, stream>>>(gh, bcnt, bbase, row_start, nchunks, N, E);
    scatter_pk<<<nchunks, 512, 0, stream>>>(src, dst, gh, pk, outcnt, E);
    matmul_mfma<<<(((N + 15) >> 4) + 3) / 4, 256, 0, stream>>>(feat, W, RW, rb, outcnt, hb8, r8, N);
    fine_kernel<<<nbuck, 256, 0, stream>>>(pk, bbase, row_start, ssrc, E, nbuck, N);
    gather_kernel<<<2048, 256, 0, stream>>>(row_start, ssrc, hb8, r8, b, out, stats, N);
    apply_kernel<<<2048, 256, 0, stream>>>(out, stats, gamma, beta, 1.0f / (float)N, (N * NCOL) / 4);
}